// Round 2
// baseline (461.677 us; speedup 1.0000x reference)
//
#include <hip/hip_runtime.h>
#include <stdint.h>

// ---- problem constants (fixed by setup_inputs) ----
constexpr int NB   = 2;       // batch
constexpr int NN   = 13824;   // nodes = 6*48*48
constexpr int NE   = 55296;   // edges = 4*NN
constexpr int H    = 32;      // node hidden
constexpr int EHID = 64;      // edge hidden
constexpr int HH   = 1024;    // H*H
constexpr int TILE = 2304;    // 48*48 nodes per tile; edge e=(t*4+d)*TILE+i has dst t*TILE+i

typedef float f32x4 __attribute__((ext_vector_type(4)));
typedef short s16x8 __attribute__((ext_vector_type(8)));
typedef __attribute__((address_space(1))) unsigned int as1_uint;
typedef __attribute__((address_space(3))) unsigned int as3_uint;

static __device__ __forceinline__ float bf2f(unsigned short u) {
    return __uint_as_float(((unsigned)u) << 16);
}
static __device__ __forceinline__ unsigned short f2bf(float f) {
    unsigned u = __float_as_uint(f);
    return (unsigned short)((u + 0x7fffu + ((u >> 16) & 1u)) >> 16);
}
static __device__ __forceinline__ void gload16(const void* g, void* l) {
    __builtin_amdgcn_global_load_lds((const as1_uint*)g, (as3_uint*)l, 16, 0, 0);
}

// ---- node projection: relu(x@pW1+pb1)@pW2+pb2 -> S0 ----
__global__ void __launch_bounds__(256)
k_proj(const float* __restrict__ in, const float* __restrict__ pW1,
       const float* __restrict__ pb1, const float* __restrict__ pW2,
       const float* __restrict__ pb2, float* __restrict__ S0) {
    int t = blockIdx.x * 256 + threadIdx.x;
    int p = t >> 5;          // row index (b*NN + n)
    int l = t & 31;
    if (p >= NB * NN) return;
    float iv = (l < 16) ? in[p * 16 + l] : 0.f;
    float hid = pb1[l];
#pragma unroll
    for (int c = 0; c < 16; c++) hid = fmaf(__shfl(iv, c, 32), pW1[c * H + l], hid);
    hid = fmaxf(hid, 0.f);
    float out = pb2[l];
#pragma unroll
    for (int h = 0; h < 32; h++) out = fmaf(__shfl(hid, h, 32), pW2[h * H + l], out);
    S0[p * H + l] = out;
}

// ---- edge hidden: a[e][k] = relu(ef@eW1+eb1), bf16 ----
__global__ void __launch_bounds__(256)
k_ehid(const float* __restrict__ ef, const float* __restrict__ eW1,
       const float* __restrict__ eb1, unsigned short* __restrict__ a) {
    int t = blockIdx.x * 256 + threadIdx.x;
    if (t >= NE * EHID) return;
    int e = t >> 6, k = t & 63;
    float v = ef[e * 2] * eW1[k] + ef[e * 2 + 1] * eW1[64 + k] + eb1[k];
    a[t] = f2bf(fmaxf(v, 0.f));
}

// ---- B prep: BpT[j'][k] = eW2[k][perm(j')] bf16  (perm: j'=o*32+h -> h*32+o) ----
__global__ void __launch_bounds__(256)
k_bprep(const float* __restrict__ eW2, const float* __restrict__ eb2,
        unsigned short* __restrict__ BpT, float* __restrict__ eb2p) {
    int t = blockIdx.x * 256 + threadIdx.x;
    if (t >= HH * EHID) return;
    int jp = t & (HH - 1);
    int k  = t >> 10;
    int src_col = (jp & 31) * 32 + (jp >> 5);
    BpT[jp * EHID + k] = f2bf(eW2[k * HH + src_col]);
    if (k == 0) eb2p[jp] = eb2[src_col];
}

// ---- We GEMM: C[e][j'] = sum_k A[e][k] * BpT[j'][k] + eb2p[j'], bf16 out ----
// A: [55296][64] bf16, BpT: [1024][64] bf16, C = WeT: [55296][1024] bf16
__global__ void __launch_bounds__(256)
k_gemm(const unsigned short* __restrict__ A, const unsigned short* __restrict__ Bt,
       const float* __restrict__ eb2p, unsigned short* __restrict__ C) {
    __shared__ unsigned char lds[32768] __attribute__((aligned(16)));
    const int tid  = threadIdx.x;
    const int wv   = tid >> 6;
    const int lane = tid & 63;
    const int lr   = lane & 15;
    const int lg   = lane >> 4;
    const int nb   = blockIdx.x;  // 0..7
    const int mb   = blockIdx.y;  // 0..431

    const unsigned char* Ag = (const unsigned char*)A  + (size_t)mb * 16384;
    const unsigned char* Bg = (const unsigned char*)Bt + (size_t)nb * 16384;

    // stage 16KB A + 16KB B; LDS dest linear, global source pre-swizzled
    // (involution XORs bits 4-6 with bits 7-9 -> conflict-free ds_read_b128)
#pragma unroll
    for (int c = 0; c < 4; c++) {
        int fbase = (wv * 4 + c) * 1024;
        int f  = fbase + lane * 16;
        int sw = f ^ (((f >> 7) & 7) << 4);
        gload16(Ag + sw, lds + fbase);
        gload16(Bg + sw, lds + 16384 + fbase);
    }
    asm volatile("s_waitcnt vmcnt(0)" ::: "memory");
    __syncthreads();

    const int wm = wv >> 1, wn = wv & 1;
    f32x4 acc[4][4] = {};
#pragma unroll
    for (int kk = 0; kk < 2; kk++) {
        s16x8 af[4], bf[4];
#pragma unroll
        for (int i = 0; i < 4; i++) {
            int la = ((wm * 64 + i * 16 + lr) * 64 + kk * 32 + lg * 8) * 2;
            la ^= ((la >> 7) & 7) << 4;
            af[i] = *(const s16x8*)(lds + la);
            int lb = ((wn * 64 + i * 16 + lr) * 64 + kk * 32 + lg * 8) * 2;
            lb ^= ((lb >> 7) & 7) << 4;
            bf[i] = *(const s16x8*)(lds + 16384 + lb);
        }
#pragma unroll
        for (int i = 0; i < 4; i++)
#pragma unroll
            for (int j = 0; j < 4; j++)
                acc[i][j] = __builtin_amdgcn_mfma_f32_16x16x32_bf16(af[i], bf[j], acc[i][j], 0, 0, 0);
    }

#pragma unroll
    for (int j = 0; j < 4; j++) {
        int col = nb * 128 + wn * 64 + j * 16 + lr;
        float bias = eb2p[col];
#pragma unroll
        for (int i = 0; i < 4; i++) {
            int row0 = mb * 128 + wm * 64 + i * 16 + lg * 4;
#pragma unroll
            for (int r = 0; r < 4; r++)
                C[(size_t)(row0 + r) * HH + col] = f2bf(acc[i][j][r] + bias);
        }
    }
}

// ---- fused step: NNConv gather + relu + GRU.  wave = 1 node (lane = b*32+o) ----
// in-edges of node n = t*TILE+i are analytically e = (t*4+k)*TILE+i, k=0..3
__global__ void __launch_bounds__(256)
k_step(const float* __restrict__ xin, float* __restrict__ xout,
       const unsigned short* __restrict__ WeT,
       const int* __restrict__ src, const float* __restrict__ conv_b,
       const float* __restrict__ gWih, const float* __restrict__ gWhh,
       const float* __restrict__ gbih, const float* __restrict__ gbhh) {
    __shared__ float WihT[32 * 96];
    __shared__ float WhhT[32 * 96];
    const int tid = threadIdx.x;
    for (int idx = tid; idx < 96 * 32; idx += 256) {
        int j = idx >> 5, h = idx & 31;
        WihT[h * 96 + j] = gWih[idx];   // WihT[h][j] = gWih[j][h]
        WhhT[h * 96 + j] = gWhh[idx];
    }
    __syncthreads();

    const int wv = tid >> 6;
    const int l  = tid & 63;
    const int b  = l >> 5;
    const int o  = l & 31;
    const int n  = blockIdx.x * 4 + wv;
    const int tt = n / TILE;
    const int ii = n - tt * TILE;

    int es[4], ss[4];
#pragma unroll
    for (int k = 0; k < 4; k++) es[k] = (tt * 4 + k) * TILE + ii;
#pragma unroll
    for (int k = 0; k < 4; k++) ss[k] = src[es[k]];

    float acc = 0.f;
#pragma unroll
    for (int k = 0; k < 4; k++) {
        float xv = xin[((size_t)b * NN + ss[k]) * H + o];
        const unsigned short* wr = WeT + (size_t)es[k] * HH + o * H;  // We[e][:,o]
#pragma unroll
        for (int c = 0; c < 4; c++) {
            s16x8 w = *(const s16x8*)(wr + c * 8);
#pragma unroll
            for (int jj = 0; jj < 8; jj++) {
                float xs = __shfl(xv, c * 8 + jj, 32);
                acc = fmaf(xs, bf2f((unsigned short)w[jj]), acc);
            }
        }
    }

    float cval = fmaxf(acc + conv_b[o], 0.f);
    float hv   = xin[((size_t)b * NN + n) * H + o];

    float axr = gbih[o],      ahr = gbhh[o];
    float axz = gbih[o + 32], ahz = gbhh[o + 32];
    float axn = gbih[o + 64], ahn = gbhh[o + 64];
#pragma unroll
    for (int h = 0; h < 32; h++) {
        float ch = __shfl(cval, h, 32);
        float hh = __shfl(hv, h, 32);
        const float* wi = &WihT[h * 96];
        const float* wh = &WhhT[h * 96];
        axr = fmaf(ch, wi[o],      axr);
        axz = fmaf(ch, wi[o + 32], axz);
        axn = fmaf(ch, wi[o + 64], axn);
        ahr = fmaf(hh, wh[o],      ahr);
        ahz = fmaf(hh, wh[o + 32], ahz);
        ahn = fmaf(hh, wh[o + 64], ahn);
    }
    float r  = 1.f / (1.f + __expf(-(axr + ahr)));
    float z  = 1.f / (1.f + __expf(-(axz + ahz)));
    float ng = tanhf(axn + r * ahn);
    float hnew = (1.f - z) * ng + z * hv;
    xout[((size_t)b * NN + n) * H + o] = hnew;
}

extern "C" void kernel_launch(void* const* d_in, const int* in_sizes, int n_in,
                              void* d_out, int out_size, void* d_ws, size_t ws_size,
                              hipStream_t stream) {
    const float* in_nodes = (const float*)d_in[0];
    const float* ef       = (const float*)d_in[1];
    const int*   src      = (const int*)d_in[2];
    const float* pW1      = (const float*)d_in[4];
    const float* pb1      = (const float*)d_in[5];
    const float* pW2      = (const float*)d_in[6];
    const float* pb2      = (const float*)d_in[7];
    const float* eW1      = (const float*)d_in[8];
    const float* eb1      = (const float*)d_in[9];
    const float* eW2      = (const float*)d_in[10];
    const float* eb2      = (const float*)d_in[11];
    const float* convb    = (const float*)d_in[12];
    const float* gWih     = (const float*)d_in[13];
    const float* gWhh     = (const float*)d_in[14];
    const float* gbih     = (const float*)d_in[15];
    const float* gbhh     = (const float*)d_in[16];

    unsigned char* ws = (unsigned char*)d_ws;
    // workspace layout (all offsets 256B-aligned), total ~124 MB
    unsigned short* WeT  = (unsigned short*)(ws + 0ull);          // 113246208 B
    unsigned short* aB   = (unsigned short*)(ws + 113246208ull);  //   7077888 B
    unsigned short* BpT  = (unsigned short*)(ws + 120324096ull);  //    131072 B
    float*          eb2p = (float*)         (ws + 120455168ull);  //      4096 B
    float*          S0   = (float*)         (ws + 120459264ull);  //   3538944 B
    float*          S1   = (float*)         (ws + 123998208ull);  //   3538944 B

    k_proj<<<(NB * NN * 32) / 256, 256, 0, stream>>>(in_nodes, pW1, pb1, pW2, pb2, S0);
    k_ehid<<<(NE * EHID) / 256, 256, 0, stream>>>(ef, eW1, eb1, aB);
    k_bprep<<<(HH * EHID) / 256, 256, 0, stream>>>(eW2, eb2, BpT, eb2p);
    dim3 g3(8, 432);
    k_gemm<<<g3, 256, 0, stream>>>(aB, BpT, eb2p, WeT);

    float* out = (float*)d_out;
    k_step<<<NN / 4, 256, 0, stream>>>(S0, S1, WeT, src, convb, gWih, gWhh, gbih, gbhh);
    k_step<<<NN / 4, 256, 0, stream>>>(S1, S0, WeT, src, convb, gWih, gWhh, gbih, gbhh);
    k_step<<<NN / 4, 256, 0, stream>>>(S0, S1, WeT, src, convb, gWih, gWhh, gbih, gbhh);
    k_step<<<NN / 4, 256, 0, stream>>>(S1, out, WeT, src, convb, gWih, gWhh, gbih, gbhh);
}

// Round 3
// 246.599 us; speedup vs baseline: 1.8722x; 1.8722x over previous
//
#include <hip/hip_runtime.h>
#include <stdint.h>

// ---- problem constants (fixed by setup_inputs) ----
constexpr int NB   = 2;       // batch
constexpr int NN   = 13824;   // nodes = 6*48*48
constexpr int NE   = 55296;   // edges = 4*NN
constexpr int H    = 32;      // node hidden
constexpr int EHID = 64;      // edge hidden
constexpr int HH   = 1024;    // H*H
constexpr int TILE = 2304;    // 48*48 nodes per tile
constexpr int NXC  = 48;

typedef float f32x4 __attribute__((ext_vector_type(4)));
typedef short s16x8 __attribute__((ext_vector_type(8)));
typedef unsigned int u32x2 __attribute__((ext_vector_type(2)));
typedef __attribute__((address_space(1))) unsigned int as1_uint;
typedef __attribute__((address_space(3))) unsigned int as3_uint;

static __device__ __forceinline__ unsigned short f2bf(float f) {
    unsigned u = __float_as_uint(f);
    return (unsigned short)((u + 0x7fffu + ((u >> 16) & 1u)) >> 16);
}
static __device__ __forceinline__ void gload16(const void* g, void* l) {
    __builtin_amdgcn_global_load_lds((const as1_uint*)g, (as3_uint*)l, 16, 0, 0);
}
static __device__ __forceinline__ float sigf(float v) {
    return 1.0f / (1.0f + __expf(-v));
}
static __device__ __forceinline__ float tanhfast(float v) {
    return 1.0f - 2.0f / (1.0f + __expf(2.0f * v));
}

// ---- fused prep: edge-hidden (bf16) | B-transpose prep | (indices split by block) ----
__global__ void __launch_bounds__(256)
k_prep(const float* __restrict__ ef, const float* __restrict__ eW1,
       const float* __restrict__ eb1, unsigned short* __restrict__ aB,
       const float* __restrict__ eW2, const float* __restrict__ eb2,
       unsigned short* __restrict__ BpT, float* __restrict__ eb2p) {
    int blk = blockIdx.x;
    if (blk < 13824) {             // edge hidden: relu(ef@eW1+eb1) -> bf16
        int t = blk * 256 + threadIdx.x;
        int e = t >> 6, k = t & 63;
        float v = ef[e * 2] * eW1[k] + ef[e * 2 + 1] * eW1[64 + k] + eb1[k];
        aB[t] = f2bf(fmaxf(v, 0.f));
    } else {                       // BpT[j'][k] = eW2[k][perm(j')], perm j'=o*32+h -> h*32+o
        int idx = (blk - 13824) * 256 + threadIdx.x;   // [0, 65536)
        int jp = idx & (HH - 1);
        int k  = idx >> 10;
        int src_col = (jp & 31) * 32 + (jp >> 5);
        BpT[jp * EHID + k] = f2bf(eW2[k * HH + src_col]);
        if (k == 0) eb2p[jp] = eb2[src_col];
    }
}

// ---- We GEMM: WeT[e][o*32+h] = We[e][h][o] (bf16), MFMA 128x128 tile ----
__global__ void __launch_bounds__(256)
k_gemm(const unsigned short* __restrict__ A, const unsigned short* __restrict__ Bt,
       const float* __restrict__ eb2p, unsigned short* __restrict__ C) {
    __shared__ unsigned char lds[32768] __attribute__((aligned(16)));
    const int tid  = threadIdx.x;
    const int wv   = tid >> 6;
    const int lane = tid & 63;
    const int lr   = lane & 15;
    const int lg   = lane >> 4;
    const int nb   = blockIdx.x;  // 0..7
    const int mb   = blockIdx.y;  // 0..431

    const unsigned char* Ag = (const unsigned char*)A  + (size_t)mb * 16384;
    const unsigned char* Bg = (const unsigned char*)Bt + (size_t)nb * 16384;

#pragma unroll
    for (int c = 0; c < 4; c++) {
        int fbase = (wv * 4 + c) * 1024;
        int f  = fbase + lane * 16;
        int sw = f ^ (((f >> 7) & 7) << 4);
        gload16(Ag + sw, lds + fbase);
        gload16(Bg + sw, lds + 16384 + fbase);
    }
    asm volatile("s_waitcnt vmcnt(0)" ::: "memory");
    __syncthreads();

    const int wm = wv >> 1, wn = wv & 1;
    f32x4 acc[4][4] = {};
#pragma unroll
    for (int kk = 0; kk < 2; kk++) {
        s16x8 af[4], bf[4];
#pragma unroll
        for (int i = 0; i < 4; i++) {
            int la = ((wm * 64 + i * 16 + lr) * 64 + kk * 32 + lg * 8) * 2;
            la ^= ((la >> 7) & 7) << 4;
            af[i] = *(const s16x8*)(lds + la);
            int lb = ((wn * 64 + i * 16 + lr) * 64 + kk * 32 + lg * 8) * 2;
            lb ^= ((lb >> 7) & 7) << 4;
            bf[i] = *(const s16x8*)(lds + 16384 + lb);
        }
#pragma unroll
        for (int i = 0; i < 4; i++)
#pragma unroll
            for (int j = 0; j < 4; j++)
                acc[i][j] = __builtin_amdgcn_mfma_f32_16x16x32_bf16(af[i], bf[j], acc[i][j], 0, 0, 0);
    }

#pragma unroll
    for (int j = 0; j < 4; j++) {
        int col = nb * 128 + wn * 64 + j * 16 + lr;
        float bias = eb2p[col];
#pragma unroll
        for (int i = 0; i < 4; i++) {
            int row0 = mb * 128 + wm * 64 + i * 16 + lg * 4;
#pragma unroll
            for (int r = 0; r < 4; r++)
                C[(size_t)(row0 + r) * HH + col] = f2bf(acc[i][j][r] + bias);
        }
    }
}

// ---- node projection (+ GRU-weight bf16 conversion in extra blocks) ----
__global__ void __launch_bounds__(256)
k_proj(const float* __restrict__ in, const float* __restrict__ pW1,
       const float* __restrict__ pb1, const float* __restrict__ pW2,
       const float* __restrict__ pb2, float* __restrict__ S0,
       unsigned short* __restrict__ xb0,
       const float* __restrict__ gWih, const float* __restrict__ gWhh,
       unsigned short* __restrict__ gWb) {
    int blk = blockIdx.x;
    if (blk >= 3456) {             // gru weight conversion: [96][32] Wih | [96][32] Whh
        int idx = (blk - 3456) * 256 + threadIdx.x;    // [0, 6144)
        gWb[idx] = f2bf(idx < 3072 ? gWih[idx] : gWhh[idx - 3072]);
        return;
    }
    int t = blk * 256 + threadIdx.x;
    int p = t >> 5;          // row index m = b*NN + n
    int l = t & 31;
    float iv = (l < 16) ? in[p * 16 + l] : 0.f;
    float hid = pb1[l];
#pragma unroll
    for (int c = 0; c < 16; c++) hid = fmaf(__shfl(iv, c, 32), pW1[c * H + l], hid);
    hid = fmaxf(hid, 0.f);
    float out = pb2[l];
#pragma unroll
    for (int h = 0; h < 32; h++) out = fmaf(__shfl(hid, h, 32), pW2[h * H + l], out);
    S0[p * H + l]  = out;
    xb0[p * H + l] = f2bf(out);
}

// ---- NNConv via MFMA: per node, 4 edges accumulate; cols 0/1 = batch ----
// wave handles 8 nodes; A = WeT fragments (global, coalesced 1KB/wave-load);
// B = xb bf16 (cols>=2 duplicate col 0/1). Output cval bf16 (post-relu+bias).
__global__ void __launch_bounds__(256)
k_conv(const unsigned short* __restrict__ xb,   // [2][NN][32] bf16
       const unsigned short* __restrict__ WeT,  // [NE][32][32] bf16 (o-major rows)
       const float* __restrict__ conv_b,
       unsigned short* __restrict__ cval) {     // [2][NN][32] bf16
    const int tid  = threadIdx.x;
    const int wv   = tid >> 6;
    const int l    = tid & 63;
    const int cl   = l & 15;    // A-row (o_local) / B-col / C-col
    const int kg   = l >> 4;    // k-group
    const int bsel = cl & 1;    // batch for B operand (cols>=2 duplicate)
    const int n0   = (blockIdx.x * 4 + wv) * 8;

    f32x4 cb0 = *(const f32x4*)(conv_b + kg * 4);
    f32x4 cb1 = *(const f32x4*)(conv_b + 16 + kg * 4);

    for (int u = 0; u < 8; ++u) {
        int n = n0 + u;
        int t = n / TILE;
        int i = n - t * TILE;
        int r = i / NXC;
        int c = i - r * NXC;
        int bt = t * TILE;
        int rm = (r == 0) ? NXC - 1 : r - 1;
        int rp = (r == NXC - 1) ? 0 : r + 1;
        int cm = (c == 0) ? NXC - 1 : c - 1;
        int cp = (c == NXC - 1) ? 0 : c + 1;
        int s0 = bt + rm * NXC + c;     // d=0: roll(+1, axis0) -> src row r-1
        int s1 = bt + rp * NXC + c;     // d=1
        int s2 = bt + r * NXC + cm;     // d=2
        int s3 = bt + r * NXC + cp;     // d=3
        int ss[4] = {s0, s1, s2, s3};

        f32x4 a0 = {}, a1 = {};
#pragma unroll
        for (int k = 0; k < 4; ++k) {
            size_t e = (size_t)((t * 4 + k) * TILE + i);
            const unsigned short* wp = WeT + e * HH;
            s16x8 af0 = *(const s16x8*)(wp + cl * 32 + kg * 8);          // o = cl
            s16x8 af1 = *(const s16x8*)(wp + 512 + cl * 32 + kg * 8);    // o = 16+cl
            s16x8 bfr = *(const s16x8*)(xb + ((size_t)(bsel * NN + ss[k])) * 32 + kg * 8);
            a0 = __builtin_amdgcn_mfma_f32_16x16x32_bf16(af0, bfr, a0, 0, 0, 0);
            a1 = __builtin_amdgcn_mfma_f32_16x16x32_bf16(af1, bfr, a1, 0, 0, 0);
        }
        // C layout: col=cl(batch), row o = kg*4+ri (a0) / 16+kg*4+ri (a1)
        if (cl < 2) {
            unsigned short* op = cval + ((size_t)(bsel * NN + n)) * 32 + kg * 4;
            u32x2 p0, p1;
            p0[0] = (unsigned)f2bf(fmaxf(a0[0] + cb0[0], 0.f)) |
                    ((unsigned)f2bf(fmaxf(a0[1] + cb0[1], 0.f)) << 16);
            p0[1] = (unsigned)f2bf(fmaxf(a0[2] + cb0[2], 0.f)) |
                    ((unsigned)f2bf(fmaxf(a0[3] + cb0[3], 0.f)) << 16);
            p1[0] = (unsigned)f2bf(fmaxf(a1[0] + cb1[0], 0.f)) |
                    ((unsigned)f2bf(fmaxf(a1[1] + cb1[1], 0.f)) << 16);
            p1[1] = (unsigned)f2bf(fmaxf(a1[2] + cb1[2], 0.f)) |
                    ((unsigned)f2bf(fmaxf(a1[3] + cb1[3], 0.f)) << 16);
            *(u32x2*)op        = p0;
            *(u32x2*)(op + 16) = p1;
        }
    }
}

// ---- GRU via MFMA: gates = [cval|h]@[Wih^T|Whh^T]; wave = one 16-row m-tile ----
__global__ void __launch_bounds__(256)
k_gru(const unsigned short* __restrict__ cval,  // bf16 [2NN][32]
      const unsigned short* __restrict__ xbin,  // bf16 h
      const float* __restrict__ hin,            // f32 h
      const unsigned short* __restrict__ gWb,   // bf16 [96][32] Wih | [96][32] Whh
      const float* __restrict__ gbih, const float* __restrict__ gbhh,
      float* __restrict__ hout, unsigned short* __restrict__ xbout) {
    const int tid = threadIdx.x;
    const int wv  = tid >> 6;
    const int l   = tid & 63;
    const int cl  = l & 15;
    const int kg  = l >> 4;
    const int mt  = blockIdx.x * 4 + wv;   // m-tile of 16 rows

    s16x8 ax = *(const s16x8*)(cval + (size_t)mt * 512 + cl * 32 + kg * 8);
    s16x8 ah = *(const s16x8*)(xbin + (size_t)mt * 512 + cl * 32 + kg * 8);

    f32x4 accx[6], acch[6];
#pragma unroll
    for (int jb = 0; jb < 6; ++jb) {
        s16x8 wx = *(const s16x8*)(gWb + (jb * 16 + cl) * 32 + kg * 8);
        s16x8 wh = *(const s16x8*)(gWb + 3072 + (jb * 16 + cl) * 32 + kg * 8);
        f32x4 z0 = {};
        f32x4 z1 = {};
        accx[jb] = __builtin_amdgcn_mfma_f32_16x16x32_bf16(ax, wx, z0, 0, 0, 0);
        acch[jb] = __builtin_amdgcn_mfma_f32_16x16x32_bf16(ah, wh, z1, 0, 0, 0);
    }

    float bihR[2] = {gbih[cl],      gbih[16 + cl]};
    float bihZ[2] = {gbih[32 + cl], gbih[48 + cl]};
    float bihN[2] = {gbih[64 + cl], gbih[80 + cl]};
    float bhhR[2] = {gbhh[cl],      gbhh[16 + cl]};
    float bhhZ[2] = {gbhh[32 + cl], gbhh[48 + cl]};
    float bhhN[2] = {gbhh[64 + cl], gbhh[80 + cl]};

#pragma unroll
    for (int hb = 0; hb < 2; ++hb) {
        const float* hp = hin  + (size_t)mt * 512 + kg * 128 + hb * 16 + cl;
        float*       op = hout + (size_t)mt * 512 + kg * 128 + hb * 16 + cl;
        unsigned short* xp = xbout + (size_t)mt * 512 + kg * 128 + hb * 16 + cl;
#pragma unroll
        for (int ri = 0; ri < 4; ++ri) {
            float rg = sigf(accx[hb][ri] + acch[hb][ri] + bihR[hb] + bhhR[hb]);
            float zg = sigf(accx[2 + hb][ri] + acch[2 + hb][ri] + bihZ[hb] + bhhZ[hb]);
            float ng = tanhfast((accx[4 + hb][ri] + bihN[hb]) +
                                rg * (acch[4 + hb][ri] + bhhN[hb]));
            float ho = hp[ri * 32];
            float hn = fmaf(zg, ho - ng, ng);
            op[ri * 32] = hn;
            xp[ri * 32] = f2bf(hn);
        }
    }
}

extern "C" void kernel_launch(void* const* d_in, const int* in_sizes, int n_in,
                              void* d_out, int out_size, void* d_ws, size_t ws_size,
                              hipStream_t stream) {
    const float* in_nodes = (const float*)d_in[0];
    const float* ef       = (const float*)d_in[1];
    const float* pW1      = (const float*)d_in[4];
    const float* pb1      = (const float*)d_in[5];
    const float* pW2      = (const float*)d_in[6];
    const float* pb2      = (const float*)d_in[7];
    const float* eW1      = (const float*)d_in[8];
    const float* eb1      = (const float*)d_in[9];
    const float* eW2      = (const float*)d_in[10];
    const float* eb2      = (const float*)d_in[11];
    const float* convb    = (const float*)d_in[12];
    const float* gWih     = (const float*)d_in[13];
    const float* gWhh     = (const float*)d_in[14];
    const float* gbih     = (const float*)d_in[15];
    const float* gbhh     = (const float*)d_in[16];

    unsigned char* ws = (unsigned char*)d_ws;
    // persistent: WeT 113.2MB | prep-only: aB (7MB, reused by xb/cval/gWb after gemm)
    unsigned short* WeT  = (unsigned short*)(ws + 0ull);          // 113246208 B
    unsigned short* aB   = (unsigned short*)(ws + 113246208ull);  //  7077888 B (prep)
    unsigned short* xb0  = (unsigned short*)(ws + 113246208ull);  //  1769472 B (steps)
    unsigned short* xb1  = (unsigned short*)(ws + 115015680ull);  //  1769472 B
    unsigned short* cval = (unsigned short*)(ws + 116785152ull);  //  1769472 B
    unsigned short* gWb  = (unsigned short*)(ws + 118554624ull);  //    12288 B
    unsigned short* BpT  = (unsigned short*)(ws + 120324096ull);  //   131072 B
    float*          eb2p = (float*)         (ws + 120455168ull);  //     4096 B
    float*          S0   = (float*)         (ws + 120459264ull);  //  3538944 B
    float*          S1   = (float*)         (ws + 123998208ull);  //  3538944 B (end 127537152)

    k_prep<<<13824 + 256, 256, 0, stream>>>(ef, eW1, eb1, aB, eW2, eb2, BpT, eb2p);
    dim3 g3(8, 432);
    k_gemm<<<g3, 256, 0, stream>>>(aB, BpT, eb2p, WeT);
    // after gemm: aB region reusable (xb0/xb1/cval/gWb)
    k_proj<<<3456 + 24, 256, 0, stream>>>(in_nodes, pW1, pb1, pW2, pb2, S0, xb0,
                                          gWih, gWhh, gWb);

    float* out = (float*)d_out;
    // step 1
    k_conv<<<432, 256, 0, stream>>>(xb0, WeT, convb, cval);
    k_gru <<<432, 256, 0, stream>>>(cval, xb0, S0, gWb, gbih, gbhh, S1, xb1);
    // step 2
    k_conv<<<432, 256, 0, stream>>>(xb1, WeT, convb, cval);
    k_gru <<<432, 256, 0, stream>>>(cval, xb1, S1, gWb, gbih, gbhh, S0, xb0);
    // step 3
    k_conv<<<432, 256, 0, stream>>>(xb0, WeT, convb, cval);
    k_gru <<<432, 256, 0, stream>>>(cval, xb0, S0, gWb, gbih, gbhh, S1, xb1);
    // step 4 -> d_out (f32)
    k_conv<<<432, 256, 0, stream>>>(xb1, WeT, convb, cval);
    k_gru <<<432, 256, 0, stream>>>(cval, xb1, S1, gWb, gbih, gbhh, out, xb0);
}

// Round 4
// 219.259 us; speedup vs baseline: 2.1056x; 1.1247x over previous
//
#include <hip/hip_runtime.h>
#include <stdint.h>

// ---- problem constants (fixed by setup_inputs) ----
constexpr int NB   = 2;       // batch
constexpr int NN   = 13824;   // nodes = 6*48*48
constexpr int NE   = 55296;   // edges = 4*NN
constexpr int H    = 32;      // node hidden
constexpr int EHID = 64;      // edge hidden
constexpr int HH   = 1024;    // H*H
constexpr int TILE = 2304;    // 48*48 nodes per tile
constexpr int NXC  = 48;

typedef float f32x4 __attribute__((ext_vector_type(4)));
typedef short s16x8 __attribute__((ext_vector_type(8)));
typedef unsigned int u32x2 __attribute__((ext_vector_type(2)));
typedef unsigned int u32x4 __attribute__((ext_vector_type(4)));
typedef __attribute__((address_space(1))) unsigned int as1_uint;
typedef __attribute__((address_space(3))) unsigned int as3_uint;

static __device__ __forceinline__ unsigned short f2bf(float f) {
    unsigned u = __float_as_uint(f);
    return (unsigned short)((u + 0x7fffu + ((u >> 16) & 1u)) >> 16);
}
static __device__ __forceinline__ unsigned packbf(float lo, float hi) {
    return (unsigned)f2bf(lo) | ((unsigned)f2bf(hi) << 16);
}
static __device__ __forceinline__ void gload16(const void* g, void* l) {
    __builtin_amdgcn_global_load_lds((const as1_uint*)g, (as3_uint*)l, 16, 0, 0);
}
static __device__ __forceinline__ float sigf(float v) {
    return 1.0f / (1.0f + __expf(-v));
}
static __device__ __forceinline__ float tanhfast(float v) {
    return 1.0f - 2.0f / (1.0f + __expf(2.0f * v));
}

// ---- prep: edge-hidden aB (bf16, x4/thread) | BpT transpose (x4/thread) ----
__global__ void __launch_bounds__(256)
k_prep(const float* __restrict__ ef, const float* __restrict__ eW1,
       const float* __restrict__ eb1, unsigned short* __restrict__ aB,
       const float* __restrict__ eW2, const float* __restrict__ eb2,
       unsigned short* __restrict__ BpT, float* __restrict__ eb2p) {
    int blk = blockIdx.x;
    if (blk < 3456) {              // aB[e][k] = relu(ef@eW1+eb1) bf16, 4 k per thread
        int t = blk * 256 + threadIdx.x;
        int e = t >> 4, kq = (t & 15) * 4;
        float f0 = ef[e * 2], f1 = ef[e * 2 + 1];
        u32x2 w;
#pragma unroll
        for (int q = 0; q < 2; q++) {
            int k = kq + q * 2;
            float v0 = fmaxf(f0 * eW1[k]     + f1 * eW1[64 + k]     + eb1[k],     0.f);
            float v1 = fmaxf(f0 * eW1[k + 1] + f1 * eW1[64 + k + 1] + eb1[k + 1], 0.f);
            w[q] = packbf(v0, v1);
        }
        *(u32x2*)(aB + e * 64 + kq) = w;
    } else {                       // BpT[j'][k] = eW2[k][perm(j')], perm j'=o*32+h -> h*32+o
        int t = (blk - 3456) * 256 + threadIdx.x;   // 16384 threads
        int jp = t >> 4, kq = (t & 15) * 4;
        int src_col = (jp & 31) * 32 + (jp >> 5);
        u32x2 w;
#pragma unroll
        for (int q = 0; q < 2; q++) {
            int k = kq + q * 2;
            w[q] = packbf(eW2[k * HH + src_col], eW2[(k + 1) * HH + src_col]);
        }
        *(u32x2*)(BpT + jp * 64 + kq) = w;
        if (kq == 0) eb2p[jp] = eb2[src_col];
    }
}

// ---- We GEMM (swapped operands): A = BpT (j' rows), B = aB (e rows) ----
// C[e][j'] written via LDS-staged coalesced dwordx4.  WeT[e][o*32+h] bf16.
__global__ void __launch_bounds__(256)
k_gemm(const unsigned short* __restrict__ Bp, const unsigned short* __restrict__ Ae,
       const float* __restrict__ eb2p, unsigned short* __restrict__ C) {
    __shared__ unsigned char lds[32768] __attribute__((aligned(16)));
    const int tid  = threadIdx.x;
    const int wv   = tid >> 6;
    const int lane = tid & 63;
    const int lr   = lane & 15;
    const int lg   = lane >> 4;
    const int jbt  = blockIdx.x;  // j' tile 0..7
    const int ebt  = blockIdx.y;  // e tile 0..431

    const unsigned char* Ag = (const unsigned char*)Bp + (size_t)jbt * 16384;
    const unsigned char* Bg = (const unsigned char*)Ae + (size_t)ebt * 16384;

    // stage 16KB A + 16KB B; LDS dest linear, global source pre-swizzled
#pragma unroll
    for (int c = 0; c < 4; c++) {
        int fbase = (wv * 4 + c) * 1024;
        int f  = fbase + lane * 16;
        int sw = f ^ (((f >> 7) & 7) << 4);
        gload16(Ag + sw, lds + fbase);
        gload16(Bg + sw, lds + 16384 + fbase);
    }
    asm volatile("s_waitcnt vmcnt(0)" ::: "memory");
    __syncthreads();

    const int wm = wv >> 1, wn = wv & 1;
    f32x4 acc[4][4] = {};
#pragma unroll
    for (int kk = 0; kk < 2; kk++) {
        s16x8 af[4], bf[4];
#pragma unroll
        for (int i = 0; i < 4; i++) {
            int la = ((wm * 64 + i * 16 + lr) * 64 + kk * 32 + lg * 8) * 2;
            la ^= ((la >> 7) & 7) << 4;
            af[i] = *(const s16x8*)(lds + la);
            int lb = ((wn * 64 + i * 16 + lr) * 64 + kk * 32 + lg * 8) * 2;
            lb ^= ((lb >> 7) & 7) << 4;
            bf[i] = *(const s16x8*)(lds + 16384 + lb);
        }
#pragma unroll
        for (int i = 0; i < 4; i++)
#pragma unroll
            for (int j = 0; j < 4; j++)
                acc[i][j] = __builtin_amdgcn_mfma_f32_16x16x32_bf16(af[i], bf[j], acc[i][j], 0, 0, 0);
    }

    // bias over j' (the C row dim)
    float bias[4][4];
#pragma unroll
    for (int i = 0; i < 4; i++)
#pragma unroll
        for (int r = 0; r < 4; r++)
            bias[i][r] = eb2p[jbt * 128 + wm * 64 + i * 16 + lg * 4 + r];

    __syncthreads();   // staging reads done everywhere; reuse lds as C tile
    // LDS C tile: [e_local 128][j' 128] bf16, involution L ^ ((e&7)<<4)
#pragma unroll
    for (int i = 0; i < 4; i++) {
#pragma unroll
        for (int j = 0; j < 4; j++) {
            int el    = wn * 64 + j * 16 + lr;
            int jbase = wm * 64 + i * 16 + lg * 4;
            int L0 = el * 256 + jbase * 2;
            int ph = L0 ^ ((el & 7) << 4);
            u32x2 w;
            w[0] = packbf(acc[i][j][0] + bias[i][0], acc[i][j][1] + bias[i][1]);
            w[1] = packbf(acc[i][j][2] + bias[i][2], acc[i][j][3] + bias[i][3]);
            *(u32x2*)(lds + ph) = w;
        }
    }
    __syncthreads();

    const size_t cbase = (size_t)(ebt * 128) * 2048 + (size_t)jbt * 256;
#pragma unroll
    for (int pass = 0; pass < 8; pass++) {
        int L2 = pass * 4096 + tid * 16;
        int el = L2 >> 8;
        int ph = L2 ^ ((el & 7) << 4);
        u32x4 v = *(const u32x4*)(lds + ph);
        *(u32x4*)((unsigned char*)C + cbase + (size_t)el * 2048 + (L2 & 255)) = v;
    }
}

// ---- node projection (+ GRU-weight bf16 conversion in extra blocks) ----
__global__ void __launch_bounds__(256)
k_proj(const float* __restrict__ in, const float* __restrict__ pW1,
       const float* __restrict__ pb1, const float* __restrict__ pW2,
       const float* __restrict__ pb2, float* __restrict__ S0,
       unsigned short* __restrict__ xb0,
       const float* __restrict__ gWih, const float* __restrict__ gWhh,
       unsigned short* __restrict__ gWb) {
    int blk = blockIdx.x;
    if (blk >= 3456) {             // gru weights: [96][32] Wih | [96][32] Whh
        int idx = (blk - 3456) * 256 + threadIdx.x;    // [0, 6144)
        gWb[idx] = f2bf(idx < 3072 ? gWih[idx] : gWhh[idx - 3072]);
        return;
    }
    int t = blk * 256 + threadIdx.x;
    int p = t >> 5;          // row index m = b*NN + n
    int l = t & 31;
    float iv = (l < 16) ? in[p * 16 + l] : 0.f;
    float hid = pb1[l];
#pragma unroll
    for (int c = 0; c < 16; c++) hid = fmaf(__shfl(iv, c, 32), pW1[c * H + l], hid);
    hid = fmaxf(hid, 0.f);
    float out = pb2[l];
#pragma unroll
    for (int h = 0; h < 32; h++) out = fmaf(__shfl(hid, h, 32), pW2[h * H + l], out);
    S0[p * H + l]  = out;
    xb0[p * H + l] = f2bf(out);
}

// ---- fused step: NNConv (MFMA) + relu -> LDS -> GRU (MFMA). 16 nodes/block ----
__global__ void __launch_bounds__(256)
k_step2(const unsigned short* __restrict__ xb_in,   // [2][NN][32] bf16 (prev x)
        const float* __restrict__ h_in,             // [2][NN][32] f32  (prev h)
        const unsigned short* __restrict__ WeT,     // [NE][32][32] bf16 o-major
        const float* __restrict__ conv_b,
        const unsigned short* __restrict__ gWb,     // [96][32] Wih | [96][32] Whh bf16
        const float* __restrict__ gbih, const float* __restrict__ gbhh,
        float* __restrict__ h_out, unsigned short* __restrict__ xb_out) {
    __shared__ unsigned short cv[2][16][32];        // conv output, 2KB
    const int tid  = threadIdx.x;
    const int wv   = tid >> 6;
    const int l    = tid & 63;
    const int cl   = l & 15;
    const int kg   = l >> 4;
    const int bsel = cl & 1;
    const int n0   = blockIdx.x * 16;

    f32x4 cb0 = *(const f32x4*)(conv_b + kg * 4);
    f32x4 cb1 = *(const f32x4*)(conv_b + 16 + kg * 4);

    // ---- conv phase: wave wv handles nodes n0+wv*4 .. +3 ----
    for (int u = 0; u < 4; ++u) {
        int n = n0 + wv * 4 + u;
        int t = n / TILE;
        int i = n - t * TILE;
        int r = i / NXC;
        int c = i - r * NXC;
        int bt = t * TILE;
        int rm = (r == 0) ? NXC - 1 : r - 1;
        int rp = (r == NXC - 1) ? 0 : r + 1;
        int cm = (c == 0) ? NXC - 1 : c - 1;
        int cp = (c == NXC - 1) ? 0 : c + 1;
        int ss[4] = {bt + rm * NXC + c, bt + rp * NXC + c,
                     bt + r * NXC + cm, bt + r * NXC + cp};

        f32x4 a0 = {}, a1 = {};
#pragma unroll
        for (int k = 0; k < 4; ++k) {
            size_t e = (size_t)((t * 4 + k) * TILE + i);
            const unsigned short* wp = WeT + e * HH;
            s16x8 af0 = *(const s16x8*)(wp + cl * 32 + kg * 8);          // o = cl
            s16x8 af1 = *(const s16x8*)(wp + 512 + cl * 32 + kg * 8);    // o = 16+cl
            s16x8 bfr = *(const s16x8*)(xb_in + ((size_t)(bsel * NN + ss[k])) * 32 + kg * 8);
            a0 = __builtin_amdgcn_mfma_f32_16x16x32_bf16(af0, bfr, a0, 0, 0, 0);
            a1 = __builtin_amdgcn_mfma_f32_16x16x32_bf16(af1, bfr, a1, 0, 0, 0);
        }
        if (cl < 2) {              // batch = cl; rows o = kg*4+r (a0), 16+kg*4+r (a1)
            int nl = wv * 4 + u;
            unsigned* cp32 = (unsigned*)&cv[cl][nl][0];
            cp32[kg * 2]     = packbf(fmaxf(a0[0] + cb0[0], 0.f), fmaxf(a0[1] + cb0[1], 0.f));
            cp32[kg * 2 + 1] = packbf(fmaxf(a0[2] + cb0[2], 0.f), fmaxf(a0[3] + cb0[3], 0.f));
            cp32[8 + kg * 2]     = packbf(fmaxf(a1[0] + cb1[0], 0.f), fmaxf(a1[1] + cb1[1], 0.f));
            cp32[8 + kg * 2 + 1] = packbf(fmaxf(a1[2] + cb1[2], 0.f), fmaxf(a1[3] + cb1[3], 0.f));
        }
    }
    __syncthreads();

    // ---- GRU phase: wave 0 -> batch 0 tile, wave 1 -> batch 1 tile ----
    if (wv < 2) {
        const int b = wv;
        const size_t mbase = (size_t)b * NN + n0;    // 16 rows mbase..mbase+15

        s16x8 ax = *(const s16x8*)&cv[b][cl][kg * 8];
        s16x8 ah = *(const s16x8*)(xb_in + (mbase + cl) * 32 + kg * 8);

        f32x4 accx[6], acch[6];
#pragma unroll
        for (int jb = 0; jb < 6; ++jb) {
            s16x8 wx = *(const s16x8*)(gWb + (jb * 16 + cl) * 32 + kg * 8);
            s16x8 wh = *(const s16x8*)(gWb + 3072 + (jb * 16 + cl) * 32 + kg * 8);
            f32x4 z0 = {};
            f32x4 z1 = {};
            accx[jb] = __builtin_amdgcn_mfma_f32_16x16x32_bf16(ax, wx, z0, 0, 0, 0);
            acch[jb] = __builtin_amdgcn_mfma_f32_16x16x32_bf16(ah, wh, z1, 0, 0, 0);
        }

        float bihR[2] = {gbih[cl],      gbih[16 + cl]};
        float bihZ[2] = {gbih[32 + cl], gbih[48 + cl]};
        float bihN[2] = {gbih[64 + cl], gbih[80 + cl]};
        float bhhR[2] = {gbhh[cl],      gbhh[16 + cl]};
        float bhhZ[2] = {gbhh[32 + cl], gbhh[48 + cl]};
        float bhhN[2] = {gbhh[64 + cl], gbhh[80 + cl]};

#pragma unroll
        for (int hb = 0; hb < 2; ++hb) {
            const float* hp = h_in  + mbase * 32 + kg * 128 + hb * 16 + cl;
            float*       op = h_out + mbase * 32 + kg * 128 + hb * 16 + cl;
            unsigned short* xp = xb_out + mbase * 32 + kg * 128 + hb * 16 + cl;
#pragma unroll
            for (int ri = 0; ri < 4; ++ri) {
                float rg = sigf(accx[hb][ri] + acch[hb][ri] + bihR[hb] + bhhR[hb]);
                float zg = sigf(accx[2 + hb][ri] + acch[2 + hb][ri] + bihZ[hb] + bhhZ[hb]);
                float ng = tanhfast((accx[4 + hb][ri] + bihN[hb]) +
                                    rg * (acch[4 + hb][ri] + bhhN[hb]));
                float ho = hp[ri * 32];
                float hn = fmaf(zg, ho - ng, ng);
                op[ri * 32] = hn;
                xp[ri * 32] = f2bf(hn);
            }
        }
    }
}

extern "C" void kernel_launch(void* const* d_in, const int* in_sizes, int n_in,
                              void* d_out, int out_size, void* d_ws, size_t ws_size,
                              hipStream_t stream) {
    const float* in_nodes = (const float*)d_in[0];
    const float* ef       = (const float*)d_in[1];
    const float* pW1      = (const float*)d_in[4];
    const float* pb1      = (const float*)d_in[5];
    const float* pW2      = (const float*)d_in[6];
    const float* pb2      = (const float*)d_in[7];
    const float* eW1      = (const float*)d_in[8];
    const float* eb1      = (const float*)d_in[9];
    const float* eW2      = (const float*)d_in[10];
    const float* eb2      = (const float*)d_in[11];
    const float* convb    = (const float*)d_in[12];
    const float* gWih     = (const float*)d_in[13];
    const float* gWhh     = (const float*)d_in[14];
    const float* gbih     = (const float*)d_in[15];
    const float* gbhh     = (const float*)d_in[16];

    unsigned char* ws = (unsigned char*)d_ws;
    // persistent: WeT 113.2MB | aB region reused by xb0/xb1/gWb after gemm
    unsigned short* WeT  = (unsigned short*)(ws + 0ull);          // 113246208 B
    unsigned short* aB   = (unsigned short*)(ws + 113246208ull);  //  7077888 B (prep/gemm only)
    unsigned short* xb0  = (unsigned short*)(ws + 113246208ull);  //  1769472 B (steps)
    unsigned short* xb1  = (unsigned short*)(ws + 115015680ull);  //  1769472 B
    unsigned short* gWb  = (unsigned short*)(ws + 118554624ull);  //    12288 B
    unsigned short* BpT  = (unsigned short*)(ws + 120324096ull);  //   131072 B
    float*          eb2p = (float*)         (ws + 120455168ull);  //     4096 B
    float*          S0   = (float*)         (ws + 120459264ull);  //  3538944 B
    float*          S1   = (float*)         (ws + 123998208ull);  //  3538944 B (end 127537152)

    k_prep<<<3456 + 64, 256, 0, stream>>>(ef, eW1, eb1, aB, eW2, eb2, BpT, eb2p);
    dim3 g3(8, 432);
    k_gemm<<<g3, 256, 0, stream>>>(BpT, aB, eb2p, WeT);
    // after gemm: aB region reusable (xb0/xb1/gWb)
    k_proj<<<3456 + 24, 256, 0, stream>>>(in_nodes, pW1, pb1, pW2, pb2, S0, xb0,
                                          gWih, gWhh, gWb);

    float* out = (float*)d_out;
    k_step2<<<864, 256, 0, stream>>>(xb0, S0, WeT, convb, gWb, gbih, gbhh, S1, xb1);
    k_step2<<<864, 256, 0, stream>>>(xb1, S1, WeT, convb, gWb, gbih, gbhh, S0, xb0);
    k_step2<<<864, 256, 0, stream>>>(xb0, S0, WeT, convb, gWb, gbih, gbhh, S1, xb1);
    k_step2<<<864, 256, 0, stream>>>(xb1, S1, WeT, convb, gWb, gbih, gbhh, out, xb0);
}

// Round 5
// 217.732 us; speedup vs baseline: 2.1204x; 1.0070x over previous
//
#include <hip/hip_runtime.h>
#include <stdint.h>

// ---- problem constants (fixed by setup_inputs) ----
constexpr int NB   = 2;       // batch
constexpr int NN   = 13824;   // nodes = 6*48*48
constexpr int NE   = 55296;   // edges = 4*NN
constexpr int H    = 32;      // node hidden
constexpr int EHID = 64;      // edge hidden
constexpr int HH   = 1024;    // H*H
constexpr int TILE = 2304;    // 48*48 nodes per tile
constexpr int NXC  = 48;

typedef float f32x4 __attribute__((ext_vector_type(4)));
typedef short s16x8 __attribute__((ext_vector_type(8)));
typedef unsigned int u32x2 __attribute__((ext_vector_type(2)));
typedef unsigned int u32x4 __attribute__((ext_vector_type(4)));
typedef __attribute__((address_space(1))) unsigned int as1_uint;
typedef __attribute__((address_space(3))) unsigned int as3_uint;

static __device__ __forceinline__ unsigned short f2bf(float f) {
    unsigned u = __float_as_uint(f);
    return (unsigned short)((u + 0x7fffu + ((u >> 16) & 1u)) >> 16);
}
static __device__ __forceinline__ unsigned packbf(float lo, float hi) {
    return (unsigned)f2bf(lo) | ((unsigned)f2bf(hi) << 16);
}
static __device__ __forceinline__ void gload16(const void* g, void* l) {
    __builtin_amdgcn_global_load_lds((const as1_uint*)g, (as3_uint*)l, 16, 0, 0);
}
static __device__ __forceinline__ float sigf(float v) {
    return 1.0f / (1.0f + __expf(-v));
}
static __device__ __forceinline__ float tanhfast(float v) {
    return 1.0f - 2.0f / (1.0f + __expf(2.0f * v));
}

// ---- fused pre-pass: aB | BpT | node projection | GRU weight bf16 ----
__global__ void __launch_bounds__(256)
k_pre(const float* __restrict__ ef, const float* __restrict__ eW1,
      const float* __restrict__ eb1, unsigned short* __restrict__ aB,
      const float* __restrict__ eW2, const float* __restrict__ eb2,
      unsigned short* __restrict__ BpT, float* __restrict__ eb2p,
      const float* __restrict__ in, const float* __restrict__ pW1,
      const float* __restrict__ pb1, const float* __restrict__ pW2,
      const float* __restrict__ pb2, float* __restrict__ S0,
      unsigned short* __restrict__ xb0,
      const float* __restrict__ gWih, const float* __restrict__ gWhh,
      unsigned short* __restrict__ gWb) {
    int blk = blockIdx.x;
    if (blk < 3456) {              // aB[e][k] = relu(ef@eW1+eb1) bf16, 4 k per thread
        int t = blk * 256 + threadIdx.x;
        int e = t >> 4, kq = (t & 15) * 4;
        float f0 = ef[e * 2], f1 = ef[e * 2 + 1];
        u32x2 w;
#pragma unroll
        for (int q = 0; q < 2; q++) {
            int k = kq + q * 2;
            float v0 = fmaxf(f0 * eW1[k]     + f1 * eW1[64 + k]     + eb1[k],     0.f);
            float v1 = fmaxf(f0 * eW1[k + 1] + f1 * eW1[64 + k + 1] + eb1[k + 1], 0.f);
            w[q] = packbf(v0, v1);
        }
        *(u32x2*)(aB + e * 64 + kq) = w;
    } else if (blk < 3520) {       // BpT[j'][k] = eW2[k][perm(j')]
        int t = (blk - 3456) * 256 + threadIdx.x;   // 16384 threads
        int jp = t >> 4, kq = (t & 15) * 4;
        int src_col = (jp & 31) * 32 + (jp >> 5);
        u32x2 w;
#pragma unroll
        for (int q = 0; q < 2; q++) {
            int k = kq + q * 2;
            w[q] = packbf(eW2[k * HH + src_col], eW2[(k + 1) * HH + src_col]);
        }
        *(u32x2*)(BpT + jp * 64 + kq) = w;
        if (kq == 0) eb2p[jp] = eb2[src_col];
    } else if (blk < 6976) {       // node projection
        int t = (blk - 3520) * 256 + threadIdx.x;
        int p = t >> 5;            // row m = b*NN + n
        int l = t & 31;
        float iv = (l < 16) ? in[p * 16 + l] : 0.f;
        float hid = pb1[l];
#pragma unroll
        for (int c = 0; c < 16; c++) hid = fmaf(__shfl(iv, c, 32), pW1[c * H + l], hid);
        hid = fmaxf(hid, 0.f);
        float out = pb2[l];
#pragma unroll
        for (int h = 0; h < 32; h++) out = fmaf(__shfl(hid, h, 32), pW2[h * H + l], out);
        S0[p * H + l]  = out;
        xb0[p * H + l] = f2bf(out);
    } else {                       // GRU weights: [96][32] Wih | [96][32] Whh
        int idx = (blk - 6976) * 256 + threadIdx.x;    // [0, 6144)
        gWb[idx] = f2bf(idx < 3072 ? gWih[idx] : gWhh[idx - 3072]);
    }
}

// ---- We GEMM (swapped operands): A = BpT (j' rows), B = aB (e rows) ----
// Output rows PERMUTED to node-major: WeTn[(n*4+k)][o*32+h] bf16.
__global__ void __launch_bounds__(256)
k_gemm(const unsigned short* __restrict__ Bp, const unsigned short* __restrict__ Ae,
       const float* __restrict__ eb2p, unsigned short* __restrict__ C) {
    __shared__ unsigned char lds[32768] __attribute__((aligned(16)));
    const int tid  = threadIdx.x;
    const int wv   = tid >> 6;
    const int lane = tid & 63;
    const int lr   = lane & 15;
    const int lg   = lane >> 4;
    const int jbt  = blockIdx.x;  // j' tile 0..7
    const int ebt  = blockIdx.y;  // e tile 0..431

    const unsigned char* Ag = (const unsigned char*)Bp + (size_t)jbt * 16384;
    const unsigned char* Bg = (const unsigned char*)Ae + (size_t)ebt * 16384;

#pragma unroll
    for (int c = 0; c < 4; c++) {
        int fbase = (wv * 4 + c) * 1024;
        int f  = fbase + lane * 16;
        int sw = f ^ (((f >> 7) & 7) << 4);
        gload16(Ag + sw, lds + fbase);
        gload16(Bg + sw, lds + 16384 + fbase);
    }
    asm volatile("s_waitcnt vmcnt(0)" ::: "memory");
    __syncthreads();

    const int wm = wv >> 1, wn = wv & 1;
    f32x4 acc[4][4] = {};
#pragma unroll
    for (int kk = 0; kk < 2; kk++) {
        s16x8 af[4], bf[4];
#pragma unroll
        for (int i = 0; i < 4; i++) {
            int la = ((wm * 64 + i * 16 + lr) * 64 + kk * 32 + lg * 8) * 2;
            la ^= ((la >> 7) & 7) << 4;
            af[i] = *(const s16x8*)(lds + la);
            int lb = ((wn * 64 + i * 16 + lr) * 64 + kk * 32 + lg * 8) * 2;
            lb ^= ((lb >> 7) & 7) << 4;
            bf[i] = *(const s16x8*)(lds + 16384 + lb);
        }
#pragma unroll
        for (int i = 0; i < 4; i++)
#pragma unroll
            for (int j = 0; j < 4; j++)
                acc[i][j] = __builtin_amdgcn_mfma_f32_16x16x32_bf16(af[i], bf[j], acc[i][j], 0, 0, 0);
    }

    float bias[4][4];
#pragma unroll
    for (int i = 0; i < 4; i++)
#pragma unroll
        for (int r = 0; r < 4; r++)
            bias[i][r] = eb2p[jbt * 128 + wm * 64 + i * 16 + lg * 4 + r];

    __syncthreads();   // reuse lds as C tile [e_local 128][j' 128] bf16
#pragma unroll
    for (int i = 0; i < 4; i++) {
#pragma unroll
        for (int j = 0; j < 4; j++) {
            int el    = wn * 64 + j * 16 + lr;
            int jbase = wm * 64 + i * 16 + lg * 4;
            int L0 = el * 256 + jbase * 2;
            int ph = L0 ^ ((el & 7) << 4);
            u32x2 w;
            w[0] = packbf(acc[i][j][0] + bias[i][0], acc[i][j][1] + bias[i][1]);
            w[1] = packbf(acc[i][j][2] + bias[i][2], acc[i][j][3] + bias[i][3]);
            *(u32x2*)(lds + ph) = w;
        }
    }
    __syncthreads();

    // node-major permuted write: e = q*TILE + i0 + el, q = t*4+k
    const int q  = (ebt * 128) / TILE;      // TILE = 18*128
    const int i0 = (ebt * 128) % TILE;
    const int tt = q >> 2, kk2 = q & 3;
    const size_t nbase = (size_t)tt * TILE + i0;
#pragma unroll
    for (int pass = 0; pass < 8; pass++) {
        int L2 = pass * 4096 + tid * 16;
        int el = L2 >> 8;
        int ph = L2 ^ ((el & 7) << 4);
        u32x4 v = *(const u32x4*)(lds + ph);
        size_t drow = (nbase + el) * 4 + kk2;
        *(u32x4*)((unsigned char*)C + drow * 2048 + (size_t)jbt * 256 + (L2 & 255)) = v;
    }
}

// ---- fused step: NNConv (MFMA, hoisted loads) + relu -> LDS -> GRU (wave 0) ----
// 8 nodes/block, wave = 2 nodes; WeTn node-major: node n rows n*4+k.
__global__ void __launch_bounds__(256)
k_step3(const unsigned short* __restrict__ xb_in,   // [2][NN][32] bf16
        const float* __restrict__ h_in,             // [2][NN][32] f32
        const unsigned short* __restrict__ WeTn,    // [NN*4][32][32] bf16 node-major
        const float* __restrict__ conv_b,
        const unsigned short* __restrict__ gWb,     // [96][32] Wih | [96][32] Whh bf16
        const float* __restrict__ gbih, const float* __restrict__ gbhh,
        float* __restrict__ h_out, unsigned short* __restrict__ xb_out) {
    __shared__ unsigned short cv[2][8][32];         // conv output, 1KB
    const int tid  = threadIdx.x;
    const int wv   = tid >> 6;
    const int l    = tid & 63;
    const int cl   = l & 15;
    const int kg   = l >> 4;
    const int bsel = cl & 1;
    const int n0   = blockIdx.x * 8;

    // ---- conv phase: wave wv -> nodes n0+wv*2, +1; hoist all 16 WeT loads ----
    int srcs[2][4];
#pragma unroll
    for (int un = 0; un < 2; ++un) {
        int n = n0 + wv * 2 + un;
        int t = n / TILE;
        int i = n - t * TILE;
        int r = i / NXC;
        int c = i - r * NXC;
        int bt = t * TILE;
        int rm = (r == 0) ? NXC - 1 : r - 1;
        int rp = (r == NXC - 1) ? 0 : r + 1;
        int cm = (c == 0) ? NXC - 1 : c - 1;
        int cp = (c == NXC - 1) ? 0 : c + 1;
        srcs[un][0] = bt + rm * NXC + c;
        srcs[un][1] = bt + rp * NXC + c;
        srcs[un][2] = bt + r * NXC + cm;
        srcs[un][3] = bt + r * NXC + cp;
    }

    s16x8 af[2][4][2];
#pragma unroll
    for (int un = 0; un < 2; ++un) {
        const unsigned short* wp = WeTn + ((size_t)(n0 + wv * 2 + un) * 4) * HH;
#pragma unroll
        for (int k = 0; k < 4; ++k) {
            af[un][k][0] = *(const s16x8*)(wp + k * HH + cl * 32 + kg * 8);
            af[un][k][1] = *(const s16x8*)(wp + k * HH + 512 + cl * 32 + kg * 8);
        }
    }

    f32x4 a[2][2] = {};
#pragma unroll
    for (int un = 0; un < 2; ++un) {
#pragma unroll
        for (int k = 0; k < 4; ++k) {
            s16x8 bfr = *(const s16x8*)(xb_in + ((size_t)(bsel * NN + srcs[un][k])) * 32 + kg * 8);
            a[un][0] = __builtin_amdgcn_mfma_f32_16x16x32_bf16(af[un][k][0], bfr, a[un][0], 0, 0, 0);
            a[un][1] = __builtin_amdgcn_mfma_f32_16x16x32_bf16(af[un][k][1], bfr, a[un][1], 0, 0, 0);
        }
    }

    f32x4 cb0 = *(const f32x4*)(conv_b + kg * 4);
    f32x4 cb1 = *(const f32x4*)(conv_b + 16 + kg * 4);
    if (cl < 2) {                  // batch = cl; rows o = kg*4+r / 16+kg*4+r
#pragma unroll
        for (int un = 0; un < 2; ++un) {
            int nl = wv * 2 + un;
            unsigned* cp32 = (unsigned*)&cv[cl][nl][0];
            cp32[kg * 2]     = packbf(fmaxf(a[un][0][0] + cb0[0], 0.f), fmaxf(a[un][0][1] + cb0[1], 0.f));
            cp32[kg * 2 + 1] = packbf(fmaxf(a[un][0][2] + cb0[2], 0.f), fmaxf(a[un][0][3] + cb0[3], 0.f));
            cp32[8 + kg * 2]     = packbf(fmaxf(a[un][1][0] + cb1[0], 0.f), fmaxf(a[un][1][1] + cb1[1], 0.f));
            cp32[8 + kg * 2 + 1] = packbf(fmaxf(a[un][1][2] + cb1[2], 0.f), fmaxf(a[un][1][3] + cb1[3], 0.f));
        }
    }
    __syncthreads();

    // ---- GRU phase: wave 0 only; m-row r=cl -> (b=r>>3, nl=r&7) ----
    if (wv == 0) {
        s16x8 ax = *(const s16x8*)&cv[cl >> 3][cl & 7][kg * 8];
        s16x8 ah = *(const s16x8*)(xb_in + ((size_t)(cl >> 3) * NN + n0 + (cl & 7)) * 32 + kg * 8);

        f32x4 accx[6], acch[6];
#pragma unroll
        for (int jb = 0; jb < 6; ++jb) {
            s16x8 wx = *(const s16x8*)(gWb + (jb * 16 + cl) * 32 + kg * 8);
            s16x8 wh = *(const s16x8*)(gWb + 3072 + (jb * 16 + cl) * 32 + kg * 8);
            f32x4 z0 = {};
            f32x4 z1 = {};
            accx[jb] = __builtin_amdgcn_mfma_f32_16x16x32_bf16(ax, wx, z0, 0, 0, 0);
            acch[jb] = __builtin_amdgcn_mfma_f32_16x16x32_bf16(ah, wh, z1, 0, 0, 0);
        }

        float bihR[2] = {gbih[cl],      gbih[16 + cl]};
        float bihZ[2] = {gbih[32 + cl], gbih[48 + cl]};
        float bihN[2] = {gbih[64 + cl], gbih[80 + cl]};
        float bhhR[2] = {gbhh[cl],      gbhh[16 + cl]};
        float bhhZ[2] = {gbhh[32 + cl], gbhh[48 + cl]};
        float bhhN[2] = {gbhh[64 + cl], gbhh[80 + cl]};

#pragma unroll
        for (int hb = 0; hb < 2; ++hb) {
#pragma unroll
            for (int ri = 0; ri < 4; ++ri) {
                int rrow = kg * 4 + ri;              // m-row -> (b, nl)
                size_t m = (size_t)(rrow >> 3) * NN + n0 + (rrow & 7);
                float rg = sigf(accx[hb][ri] + acch[hb][ri] + bihR[hb] + bhhR[hb]);
                float zg = sigf(accx[2 + hb][ri] + acch[2 + hb][ri] + bihZ[hb] + bhhZ[hb]);
                float ng = tanhfast((accx[4 + hb][ri] + bihN[hb]) +
                                    rg * (acch[4 + hb][ri] + bhhN[hb]));
                float ho = h_in[m * 32 + hb * 16 + cl];
                float hn = fmaf(zg, ho - ng, ng);
                h_out[m * 32 + hb * 16 + cl]  = hn;
                xb_out[m * 32 + hb * 16 + cl] = f2bf(hn);
            }
        }
    }
}

extern "C" void kernel_launch(void* const* d_in, const int* in_sizes, int n_in,
                              void* d_out, int out_size, void* d_ws, size_t ws_size,
                              hipStream_t stream) {
    const float* in_nodes = (const float*)d_in[0];
    const float* ef       = (const float*)d_in[1];
    const float* pW1      = (const float*)d_in[4];
    const float* pb1      = (const float*)d_in[5];
    const float* pW2      = (const float*)d_in[6];
    const float* pb2      = (const float*)d_in[7];
    const float* eW1      = (const float*)d_in[8];
    const float* eb1      = (const float*)d_in[9];
    const float* eW2      = (const float*)d_in[10];
    const float* eb2      = (const float*)d_in[11];
    const float* convb    = (const float*)d_in[12];
    const float* gWih     = (const float*)d_in[13];
    const float* gWhh     = (const float*)d_in[14];
    const float* gbih     = (const float*)d_in[15];
    const float* gbhh     = (const float*)d_in[16];

    unsigned char* ws = (unsigned char*)d_ws;
    unsigned short* WeTn = (unsigned short*)(ws + 0ull);          // 113246208 B
    unsigned short* aB   = (unsigned short*)(ws + 113246208ull);  //   7077888 B
    unsigned short* BpT  = (unsigned short*)(ws + 120324096ull);  //    131072 B
    float*          eb2p = (float*)         (ws + 120455168ull);  //      4096 B
    float*          S0   = (float*)         (ws + 120459264ull);  //   3538944 B
    float*          S1   = (float*)         (ws + 123998208ull);  //   3538944 B
    unsigned short* xb0  = (unsigned short*)(ws + 127537152ull);  //   1769472 B
    unsigned short* xb1  = (unsigned short*)(ws + 129306624ull);  //   1769472 B
    unsigned short* gWb  = (unsigned short*)(ws + 131076096ull);  //     12288 B (end ~131.1MB)

    k_pre<<<7000, 256, 0, stream>>>(ef, eW1, eb1, aB, eW2, eb2, BpT, eb2p,
                                    in_nodes, pW1, pb1, pW2, pb2, S0, xb0,
                                    gWih, gWhh, gWb);
    dim3 g3(8, 432);
    k_gemm<<<g3, 256, 0, stream>>>(BpT, aB, eb2p, WeTn);

    float* out = (float*)d_out;
    k_step3<<<1728, 256, 0, stream>>>(xb0, S0, WeTn, convb, gWb, gbih, gbhh, S1, xb1);
    k_step3<<<1728, 256, 0, stream>>>(xb1, S1, WeTn, convb, gWb, gbih, gbhh, S0, xb0);
    k_step3<<<1728, 256, 0, stream>>>(xb0, S0, WeTn, convb, gWb, gbih, gbhh, S1, xb1);
    k_step3<<<1728, 256, 0, stream>>>(xb1, S1, WeTn, convb, gWb, gbih, gbhh, out, xb0);
}